// Round 3
// baseline (3537.973 us; speedup 1.0000x reference)
//
#include <hip/hip_runtime.h>

#define N_NODES 50000
#define N_GENES 256
#define N_EDGES 800000
#define NUM_ITERS 10
#define SCAN_BLK 1024
#define N_SCAN_BLKS ((N_NODES + SCAN_BLK - 1) / SCAN_BLK)   // 49

#define SLICE_GENES 16
#define N_SLICES 16                          // 16 x 16 genes = 256
#define NODES_PER_BLOCK 8                    // 4 waves x 2 nodes
#define BLOCKS_PER_SLICE (N_NODES / NODES_PER_BLOCK)   // 6250
#define HALF_BLOCKS (8 * BLOCKS_PER_SLICE)   // 50000 (slices 0-7)
#define PROP_GRID (N_SLICES * BLOCKS_PER_SLICE)        // 100000

// ---------------- CSR build (once per launch) -----------------------------

__global__ void hist_kernel(const int* __restrict__ dst, int* __restrict__ counts) {
    int e = blockIdx.x * blockDim.x + threadIdx.x;
    if (e < N_EDGES) atomicAdd(&counts[dst[e]], 1);
}

__global__ __launch_bounds__(SCAN_BLK) void scan1_kernel(
        const int* __restrict__ counts, int* __restrict__ offs,
        int* __restrict__ bsums) {
    int i = blockIdx.x * SCAN_BLK + threadIdx.x;
    int lane = threadIdx.x & 63, wid = threadIdx.x >> 6;
    int v = (i < N_NODES) ? counts[i] : 0;
    int x = v;
    #pragma unroll
    for (int o = 1; o < 64; o <<= 1) {
        int t = __shfl_up(x, o, 64);
        if (lane >= o) x += t;
    }
    __shared__ int wsum[16];
    if (lane == 63) wsum[wid] = x;
    __syncthreads();
    if (wid == 0 && lane < 16) {
        int y = wsum[lane];
        #pragma unroll
        for (int o = 1; o < 16; o <<= 1) {
            int t = __shfl_up(y, o, 64);
            if (lane >= o) y += t;
        }
        wsum[lane] = y;
    }
    __syncthreads();
    int pref = (wid > 0) ? wsum[wid - 1] : 0;
    int incl = x + pref;
    if (i < N_NODES) offs[i] = incl - v;
    if (threadIdx.x == SCAN_BLK - 1) bsums[blockIdx.x] = incl;
}

__global__ void scan2_kernel(const int* __restrict__ bsums,
                             int* __restrict__ bpref,
                             int* __restrict__ offs_total) {
    int lane = threadIdx.x;  // 64 threads
    int v = (lane < N_SCAN_BLKS) ? bsums[lane] : 0;
    int x = v;
    #pragma unroll
    for (int o = 1; o < 64; o <<= 1) {
        int t = __shfl_up(x, o, 64);
        if (lane >= o) x += t;
    }
    if (lane < N_SCAN_BLKS) bpref[lane] = x - v;
    if (lane == 63) offs_total[0] = x;
}

__global__ __launch_bounds__(SCAN_BLK) void scan3_kernel(
        int* __restrict__ offs, const int* __restrict__ bpref,
        int* __restrict__ cursor) {
    int i = blockIdx.x * SCAN_BLK + threadIdx.x;
    if (i < N_NODES) {
        int o = offs[i] + bpref[blockIdx.x];
        offs[i] = o;
        cursor[i] = o;
    }
}

// scatter: CSR payload as u16 src + f32 w (6B/edge; src < 50000 < 65536)
__global__ void scatter_kernel(const int* __restrict__ dst,
                               const int* __restrict__ src,
                               const float* __restrict__ w,
                               int* __restrict__ cursor,
                               unsigned short* __restrict__ ssrc,
                               float* __restrict__ sw) {
    int e = blockIdx.x * blockDim.x + threadIdx.x;
    if (e < N_EDGES) {
        int d = dst[e];
        int p = atomicAdd(&cursor[d], 1);
        ssrc[p] = (unsigned short)src[e];
        sw[p]   = w[e];
    }
}

// ---------------- Gene-sliced propagation ---------------------------------
// Slice s (16 genes, 3.2 MB over all rows) is processed only by blocks with
// blockIdx%8 == s%8 -> pinned to one XCD's 4MB L2 -> gathers are L2 hits.
// Wave layout: lane = 16*edge_sublane + gene. Edge metadata + clamp + stores
// use nontemporal hints so streams don't evict the resident slice.

__global__ __launch_bounds__(256) void prop_kernel(
        const float* __restrict__ hin,
        const float* __restrict__ x,
        const int* __restrict__ offsets,
        const unsigned short* __restrict__ ssrc,
        const float* __restrict__ sw,
        float* __restrict__ out,
        int hin_nm, int out_nm) {
    int b = blockIdx.x;
    int slice, grp;
    if (b < HALF_BLOCKS) { slice = b & 7;                    grp = b >> 3; }
    else { int bp = b - HALF_BLOCKS; slice = 8 + (bp & 7);   grp = bp >> 3; }
    int wid  = threadIdx.x >> 6;
    int lane = threadIdx.x & 63;
    int el   = lane >> 4;     // edge sub-lane 0..3
    int g    = lane & 15;     // gene within slice

    size_t hin_off; int hstride;
    if (hin_nm) { hin_off = (size_t)slice * SLICE_GENES;               hstride = N_GENES; }
    else        { hin_off = (size_t)slice * (N_NODES * SLICE_GENES);   hstride = SLICE_GENES; }
    const float* hbase = hin + hin_off + g;

    int node0 = grp * NODES_PER_BLOCK + wid * 2;  // exact: 6250*8 = 50000
    int o0 = offsets[node0];
    int o1 = offsets[node0 + 1];
    int o2 = offsets[node0 + 2];

    // two interleaved edge streams (node0, node1) with metadata prefetch
    float acc0 = 0.f, acc1 = 0.f;
    int  i0 = o0 + el, i1 = o1 + el;
    bool v0 = i0 < o1, v1 = i1 < o2;
    int s0 = 0, s1 = 0; float w0 = 0.f, w1 = 0.f;
    if (v0) { s0 = __builtin_nontemporal_load(&ssrc[i0]);
              w0 = __builtin_nontemporal_load(&sw[i0]); }
    if (v1) { s1 = __builtin_nontemporal_load(&ssrc[i1]);
              w1 = __builtin_nontemporal_load(&sw[i1]); }
    while (v0 || v1) {
        float g0 = 0.f, g1 = 0.f;
        if (v0) g0 = hbase[(size_t)s0 * hstride];
        if (v1) g1 = hbase[(size_t)s1 * hstride];
        int ni0 = i0 + 4, ni1 = i1 + 4;
        bool nv0 = ni0 < o1, nv1 = ni1 < o2;
        int ns0 = 0, ns1 = 0; float nw0 = 0.f, nw1 = 0.f;
        if (nv0) { ns0 = __builtin_nontemporal_load(&ssrc[ni0]);
                   nw0 = __builtin_nontemporal_load(&sw[ni0]); }
        if (nv1) { ns1 = __builtin_nontemporal_load(&ssrc[ni1]);
                   nw1 = __builtin_nontemporal_load(&sw[ni1]); }
        acc0 += w0 * g0;
        acc1 += w1 * g1;
        i0 = ni0; i1 = ni1; v0 = nv0; v1 = nv1;
        s0 = ns0; s1 = ns1; w0 = nw0; w1 = nw1;
    }

    // reduce across the 4 edge sub-lanes (gene g stays in-lane)
    acc0 += __shfl_xor(acc0, 16);
    acc0 += __shfl_xor(acc0, 32);
    acc1 += __shfl_xor(acc1, 16);
    acc1 += __shfl_xor(acc1, 32);

    if (lane < 16) {
        #pragma unroll
        for (int sub = 0; sub < 2; ++sub) {
            int   node = node0 + sub;
            float acc  = sub ? acc1 : acc0;
            float ov = __builtin_nontemporal_load(&x[(size_t)node * N_GENES + slice * SLICE_GENES + g]);
            float r  = (ov != 0.f) ? ov : acc;
            size_t oidx = out_nm
                ? (size_t)node * N_GENES + slice * SLICE_GENES + g
                : (size_t)slice * (N_NODES * SLICE_GENES) + (size_t)node * SLICE_GENES + g;
            __builtin_nontemporal_store(r, &out[oidx]);
        }
    }
}

// --------------------------------------------------------------------------

static inline size_t align_up(size_t x, size_t a) { return (x + a - 1) & ~(a - 1); }

extern "C" void kernel_launch(void* const* d_in, const int* in_sizes, int n_in,
                              void* d_out, int out_size, void* d_ws, size_t ws_size,
                              hipStream_t stream) {
    const float* x    = (const float*)d_in[0];   // [N_NODES, N_GENES]
    const int*   eidx = (const int*)d_in[1];     // [2, N_EDGES]: row0 = dst, row1 = src
    const float* ew   = (const float*)d_in[2];   // [N_EDGES]
    float*       out  = (float*)d_out;

    const int* dst = eidx;
    const int* src = eidx + N_EDGES;

    // workspace layout (~57 MB)
    char* ws = (char*)d_ws;
    size_t off = 0;
    float*          hA      = (float*)(ws + off);          off += align_up((size_t)N_NODES * N_GENES * 4, 256);
    unsigned short* ssrc16  = (unsigned short*)(ws + off); off += align_up((size_t)N_EDGES * 2, 256);
    float*          swt     = (float*)(ws + off);          off += align_up((size_t)N_EDGES * 4, 256);
    int*            counts  = (int*)(ws + off);            off += align_up((size_t)N_NODES * 4, 256);
    int*            offsets = (int*)(ws + off);            off += align_up((size_t)(N_NODES + 1) * 4, 256);
    int*            cursor  = (int*)(ws + off);            off += align_up((size_t)N_NODES * 4, 256);
    int*            bsums   = (int*)(ws + off);            off += align_up((size_t)N_SCAN_BLKS * 4, 256);
    int*            bpref   = (int*)(ws + off);            off += align_up((size_t)N_SCAN_BLKS * 4, 256);
    (void)ws_size;

    // ---- build CSR by destination ----
    hipMemsetAsync(counts, 0, (size_t)N_NODES * 4, stream);
    hist_kernel<<<(N_EDGES + 255) / 256, 256, 0, stream>>>(dst, counts);
    scan1_kernel<<<N_SCAN_BLKS, SCAN_BLK, 0, stream>>>(counts, offsets, bsums);
    scan2_kernel<<<1, 64, 0, stream>>>(bsums, bpref, &offsets[N_NODES]);
    scan3_kernel<<<N_SCAN_BLKS, SCAN_BLK, 0, stream>>>(offsets, bpref, cursor);
    scatter_kernel<<<(N_EDGES + 255) / 256, 256, 0, stream>>>(dst, src, ew, cursor, ssrc16, swt);

    // ---- 10 sliced propagation iterations ----
    // ping-pong: hA (ws, slice-major) <-> d_out used as slice-major scratch;
    // final iteration reads hA and writes node-major f32 into d_out.
    const float* hin = x; int hin_nm = 1;
    for (int it = 0; it < NUM_ITERS; ++it) {
        float* hout; int out_nm;
        if (it == NUM_ITERS - 1) { hout = out; out_nm = 1; }
        else if ((it & 1) == 0)  { hout = hA;  out_nm = 0; }   // even -> A
        else                     { hout = out; out_nm = 0; }   // odd  -> d_out scratch
        prop_kernel<<<PROP_GRID, 256, 0, stream>>>(hin, x, offsets, ssrc16, swt,
                                                   hout, hin_nm, out_nm);
        hin = hout; hin_nm = out_nm;
    }
}

// Round 6
// 768.737 us; speedup vs baseline: 4.6023x; 4.6023x over previous
//
#include <hip/hip_runtime.h>

#define N_NODES 50000
#define N_GENES 256
#define N_EDGES 800000
#define NUM_ITERS 10
#define SCAN_BLK 1024
#define N_SCAN_BLKS ((N_NODES + SCAN_BLK - 1) / SCAN_BLK)   // 49

typedef unsigned short u16;

struct u16x4 { u16 x, y, z, w; };

static __device__ __forceinline__ float bf2f(u16 b) {
    return __uint_as_float(((unsigned)b) << 16);
}
static __device__ __forceinline__ u16 f2bf(float f) {
    unsigned u = __float_as_uint(f);
    return (u16)((u + 0x7fffu + ((u >> 16) & 1u)) >> 16);   // RNE
}

// ---------------- CSR build (once per launch) -----------------------------

__global__ void hist_kernel(const int* __restrict__ dst, int* __restrict__ counts) {
    int e = blockIdx.x * blockDim.x + threadIdx.x;
    if (e < N_EDGES) atomicAdd(&counts[dst[e]], 1);
}

__global__ __launch_bounds__(SCAN_BLK) void scan1_kernel(
        const int* __restrict__ counts, int* __restrict__ offs,
        int* __restrict__ bsums) {
    int i = blockIdx.x * SCAN_BLK + threadIdx.x;
    int lane = threadIdx.x & 63, wid = threadIdx.x >> 6;
    int v = (i < N_NODES) ? counts[i] : 0;
    int x = v;
    #pragma unroll
    for (int o = 1; o < 64; o <<= 1) {
        int t = __shfl_up(x, o, 64);
        if (lane >= o) x += t;
    }
    __shared__ int wsum[16];
    if (lane == 63) wsum[wid] = x;
    __syncthreads();
    if (wid == 0 && lane < 16) {
        int y = wsum[lane];
        #pragma unroll
        for (int o = 1; o < 16; o <<= 1) {
            int t = __shfl_up(y, o, 64);
            if (lane >= o) y += t;
        }
        wsum[lane] = y;
    }
    __syncthreads();
    int pref = (wid > 0) ? wsum[wid - 1] : 0;
    int incl = x + pref;
    if (i < N_NODES) offs[i] = incl - v;
    if (threadIdx.x == SCAN_BLK - 1) bsums[blockIdx.x] = incl;
}

__global__ void scan2_kernel(const int* __restrict__ bsums,
                             int* __restrict__ bpref,
                             int* __restrict__ offs_total) {
    int lane = threadIdx.x;  // 64 threads
    int v = (lane < N_SCAN_BLKS) ? bsums[lane] : 0;
    int x = v;
    #pragma unroll
    for (int o = 1; o < 64; o <<= 1) {
        int t = __shfl_up(x, o, 64);
        if (lane >= o) x += t;
    }
    if (lane < N_SCAN_BLKS) bpref[lane] = x - v;
    if (lane == 63) offs_total[0] = x;
}

__global__ __launch_bounds__(SCAN_BLK) void scan3_kernel(
        int* __restrict__ offs, const int* __restrict__ bpref,
        int* __restrict__ cursor) {
    int i = blockIdx.x * SCAN_BLK + threadIdx.x;
    if (i < N_NODES) {
        int o = offs[i] + bpref[blockIdx.x];
        offs[i] = o;
        cursor[i] = o;
    }
}

__global__ void scatter_kernel(const int* __restrict__ dst,
                               const int* __restrict__ src,
                               const float* __restrict__ w,
                               int* __restrict__ cursor,
                               int2* __restrict__ edges) {
    int e = blockIdx.x * blockDim.x + threadIdx.x;
    if (e < N_EDGES) {
        int d = dst[e];
        int p = atomicAdd(&cursor[d], 1);
        edges[p] = make_int2(src[e], __float_as_int(w[e]));
    }
}

// x (f32) -> xb (bf16), 8 elems per thread
__global__ __launch_bounds__(256) void cvt_kernel(const float* __restrict__ x,
                                                  u16* __restrict__ xb) {
    int i = (blockIdx.x * blockDim.x + threadIdx.x) * 8;
    if (i >= N_NODES * N_GENES) return;
    float4 a = *reinterpret_cast<const float4*>(&x[i]);
    float4 b = *reinterpret_cast<const float4*>(&x[i + 4]);
    u16x4 r0 = { f2bf(a.x), f2bf(a.y), f2bf(a.z), f2bf(a.w) };
    u16x4 r1 = { f2bf(b.x), f2bf(b.y), f2bf(b.z), f2bf(b.w) };
    *reinterpret_cast<u16x4*>(&xb[i])     = r0;
    *reinterpret_cast<u16x4*>(&xb[i + 4]) = r1;
}

// ---------------- Propagation (bf16 h, f32 accumulate) --------------------
// One wave per dst node; lane holds genes 4l..4l+3. Edge list loaded
// lane-parallel, (src,w) broadcast via shfl; 8 row-gathers in flight.

__global__ __launch_bounds__(256) void prop_kernel_b(
        const u16* __restrict__ hin,
        const u16* __restrict__ xb,
        const int* __restrict__ offsets,
        const int2* __restrict__ edges,
        u16* __restrict__ out) {
    int node = blockIdx.x * 4 + (threadIdx.x >> 6);
    if (node >= N_NODES) return;
    int lane = threadIdx.x & 63;
    int g4 = lane << 2;

    int beg = offsets[node];
    int end = offsets[node + 1];

    float a0 = 0.f, a1 = 0.f, a2 = 0.f, a3 = 0.f;

    for (int base = beg; base < end; base += 64) {
        int cnt = end - base;
        if (cnt > 64) cnt = 64;
        int2 el = make_int2(0, 0);
        if (lane < cnt) el = edges[base + lane];

        int k = 0;
        for (; k + 8 <= cnt; k += 8) {
            int s[8]; float w[8];
            #pragma unroll
            for (int j = 0; j < 8; ++j) {
                s[j] = __shfl(el.x, k + j);
                w[j] = __int_as_float(__shfl(el.y, k + j));
            }
            u16x4 r[8];
            #pragma unroll
            for (int j = 0; j < 8; ++j)
                r[j] = *reinterpret_cast<const u16x4*>(&hin[(size_t)s[j] * N_GENES + g4]);
            #pragma unroll
            for (int j = 0; j < 8; ++j) {
                a0 += w[j] * bf2f(r[j].x);
                a1 += w[j] * bf2f(r[j].y);
                a2 += w[j] * bf2f(r[j].z);
                a3 += w[j] * bf2f(r[j].w);
            }
        }
        for (; k < cnt; ++k) {
            int   s = __shfl(el.x, k);
            float w = __int_as_float(__shfl(el.y, k));
            u16x4 r = *reinterpret_cast<const u16x4*>(&hin[(size_t)s * N_GENES + g4]);
            a0 += w * bf2f(r.x);
            a1 += w * bf2f(r.y);
            a2 += w * bf2f(r.z);
            a3 += w * bf2f(r.w);
        }
    }

    size_t idx = (size_t)node * N_GENES + g4;
    u16x4 o = *reinterpret_cast<const u16x4*>(&xb[idx]);
    u16x4 res;
    res.x = o.x ? o.x : f2bf(a0);   // x >= 0, so bits==0 <=> value==0
    res.y = o.y ? o.y : f2bf(a1);
    res.z = o.z ? o.z : f2bf(a2);
    res.w = o.w ? o.w : f2bf(a3);
    *reinterpret_cast<u16x4*>(&out[idx]) = res;
}

// Final iteration: bf16 gather, f32 accumulate, clamp with pristine f32 x,
// write f32 output.
__global__ __launch_bounds__(256) void prop_kernel_final(
        const u16* __restrict__ hin,
        const float* __restrict__ x,
        const int* __restrict__ offsets,
        const int2* __restrict__ edges,
        float* __restrict__ out) {
    int node = blockIdx.x * 4 + (threadIdx.x >> 6);
    if (node >= N_NODES) return;
    int lane = threadIdx.x & 63;
    int g4 = lane << 2;

    int beg = offsets[node];
    int end = offsets[node + 1];

    float a0 = 0.f, a1 = 0.f, a2 = 0.f, a3 = 0.f;

    for (int base = beg; base < end; base += 64) {
        int cnt = end - base;
        if (cnt > 64) cnt = 64;
        int2 el = make_int2(0, 0);
        if (lane < cnt) el = edges[base + lane];

        int k = 0;
        for (; k + 8 <= cnt; k += 8) {
            int s[8]; float w[8];
            #pragma unroll
            for (int j = 0; j < 8; ++j) {
                s[j] = __shfl(el.x, k + j);
                w[j] = __int_as_float(__shfl(el.y, k + j));
            }
            u16x4 r[8];
            #pragma unroll
            for (int j = 0; j < 8; ++j)
                r[j] = *reinterpret_cast<const u16x4*>(&hin[(size_t)s[j] * N_GENES + g4]);
            #pragma unroll
            for (int j = 0; j < 8; ++j) {
                a0 += w[j] * bf2f(r[j].x);
                a1 += w[j] * bf2f(r[j].y);
                a2 += w[j] * bf2f(r[j].z);
                a3 += w[j] * bf2f(r[j].w);
            }
        }
        for (; k < cnt; ++k) {
            int   s = __shfl(el.x, k);
            float w = __int_as_float(__shfl(el.y, k));
            u16x4 r = *reinterpret_cast<const u16x4*>(&hin[(size_t)s * N_GENES + g4]);
            a0 += w * bf2f(r.x);
            a1 += w * bf2f(r.y);
            a2 += w * bf2f(r.z);
            a3 += w * bf2f(r.w);
        }
    }

    size_t idx = (size_t)node * N_GENES + g4;
    float4 o = *reinterpret_cast<const float4*>(&x[idx]);
    float4 res;
    res.x = (o.x != 0.f) ? o.x : a0;
    res.y = (o.y != 0.f) ? o.y : a1;
    res.z = (o.z != 0.f) ? o.z : a2;
    res.w = (o.w != 0.f) ? o.w : a3;
    *reinterpret_cast<float4*>(&out[idx]) = res;
}

// --------------------------------------------------------------------------

static inline size_t align_up(size_t x, size_t a) { return (x + a - 1) & ~(a - 1); }

extern "C" void kernel_launch(void* const* d_in, const int* in_sizes, int n_in,
                              void* d_out, int out_size, void* d_ws, size_t ws_size,
                              hipStream_t stream) {
    const float* x    = (const float*)d_in[0];   // [N_NODES, N_GENES]
    const int*   eidx = (const int*)d_in[1];     // [2, N_EDGES]: row0 = dst, row1 = src
    const float* ew   = (const float*)d_in[2];   // [N_EDGES]
    float*       out  = (float*)d_out;

    const int* dst = eidx;
    const int* src = eidx + N_EDGES;

    // workspace layout (~60 MB)
    char* ws = (char*)d_ws;
    size_t off = 0;
    u16*   xb      = (u16*) (ws + off); off += align_up((size_t)N_NODES * N_GENES * 2, 256);
    u16*   hb0     = (u16*) (ws + off); off += align_up((size_t)N_NODES * N_GENES * 2, 256);
    int2*  edges   = (int2*)(ws + off); off += align_up((size_t)N_EDGES * 8, 256);
    int*   counts  = (int*) (ws + off); off += align_up((size_t)N_NODES * 4, 256);
    int*   offsets = (int*) (ws + off); off += align_up((size_t)(N_NODES + 1) * 4, 256);
    int*   cursor  = (int*) (ws + off); off += align_up((size_t)N_NODES * 4, 256);
    int*   bsums   = (int*) (ws + off); off += align_up((size_t)N_SCAN_BLKS * 4, 256);
    int*   bpref   = (int*) (ws + off); off += align_up((size_t)N_SCAN_BLKS * 4, 256);
    (void)ws_size;

    u16* hbO = (u16*)d_out;   // d_out doubles as bf16 scratch (25.6 of 51.2 MB)

    // ---- build CSR by destination + bf16 copy of x ----
    hipMemsetAsync(counts, 0, (size_t)N_NODES * 4, stream);
    hist_kernel<<<(N_EDGES + 255) / 256, 256, 0, stream>>>(dst, counts);
    scan1_kernel<<<N_SCAN_BLKS, SCAN_BLK, 0, stream>>>(counts, offsets, bsums);
    scan2_kernel<<<1, 64, 0, stream>>>(bsums, bpref, &offsets[N_NODES]);
    scan3_kernel<<<N_SCAN_BLKS, SCAN_BLK, 0, stream>>>(offsets, bpref, cursor);
    scatter_kernel<<<(N_EDGES + 255) / 256, 256, 0, stream>>>(dst, src, ew, cursor, edges);
    cvt_kernel<<<(N_NODES * N_GENES / 8 + 255) / 256, 256, 0, stream>>>(x, xb);

    // ---- 10 propagation iterations ----
    // iters 0..8 in bf16: even -> hb0, odd -> hbO (d_out scratch); it8 -> hb0.
    // iter 9 reads hb0, clamps with f32 x, writes f32 d_out.
    const int grid = (N_NODES + 3) / 4;
    const u16* hin = xb;
    for (int it = 0; it < NUM_ITERS - 1; ++it) {
        u16* hout = (it & 1) ? hbO : hb0;
        prop_kernel_b<<<grid, 256, 0, stream>>>(hin, xb, offsets, edges, hout);
        hin = hout;
    }
    prop_kernel_final<<<grid, 256, 0, stream>>>(hin, x, offsets, edges, out);
}